// Round 7
// baseline (325.311 us; speedup 1.0000x reference)
//
#include <hip/hip_runtime.h>

typedef __bf16 bf16_t;
typedef __bf16 bf16x8 __attribute__((ext_vector_type(8)));
typedef __bf16 bf16x4 __attribute__((ext_vector_type(4)));
typedef float f32x4 __attribute__((ext_vector_type(4)));

static constexpr int Bb = 4, Hh = 12, Nn = 1024, Cc = 768, HD = 64;
static constexpr int OUT0 = Bb * Nn * Cc;  // 3145728 floats

// ---------------- convert fp32 -> bf16 (x, qkv_w, proj_w) ----------------
__global__ __launch_bounds__(256) void convert_all(
    const float* __restrict__ x, const float* __restrict__ qw, const float* __restrict__ pw,
    bf16_t* __restrict__ xb, bf16_t* __restrict__ qwb, bf16_t* __restrict__ pwb) {
  const int NX = (Bb * Nn * Cc) / 4;  // 786432 float4s
  const int NQ = (3 * Cc * Cc) / 4;   // 442368
  int i = blockIdx.x * 256 + threadIdx.x;
  const float4* src;
  bf16_t* dst;
  int off;
  if (i < NX) { src = (const float4*)x; dst = xb; off = i; }
  else if (i < NX + NQ) { src = (const float4*)qw; dst = qwb; off = i - NX; }
  else { src = (const float4*)pw; dst = pwb; off = i - NX - NQ; }
  float4 v = src[off];
  bf16x4 o;
  o[0] = (bf16_t)v.x; o[1] = (bf16_t)v.y; o[2] = (bf16_t)v.z; o[3] = (bf16_t)v.w;
  *(bf16x4*)(dst + (size_t)off * 4) = o;
}

// ---------------- 128x128-tile bf16 MFMA GEMM -----------------------------
template <int MODE>
__global__ __launch_bounds__(256) void gemm_bt(
    const bf16_t* __restrict__ A, const bf16_t* __restrict__ Bm, int N, int K,
    bf16_t* __restrict__ q_bf, bf16_t* __restrict__ k_bf, bf16_t* __restrict__ vT_bf,
    float* __restrict__ outF, const float* __restrict__ bias) {
  __shared__ bf16_t As[128 * 40];
  __shared__ bf16_t Bs[128 * 40];
  const int tid = threadIdx.x;
  const int lane = tid & 63;
  const int w = tid >> 6;
  const int wr = w >> 1, wc = w & 1;
  const int g = lane >> 4, r = lane & 15;
  const int ntiles = N >> 7;
  const int m0 = (blockIdx.x / ntiles) << 7;
  const int n0 = (blockIdx.x % ntiles) << 7;

  const f32x4 fz = {0.f, 0.f, 0.f, 0.f};
  f32x4 acc[4][4];
#pragma unroll
  for (int i = 0; i < 4; i++)
#pragma unroll
    for (int j = 0; j < 4; j++) acc[i][j] = fz;

  for (int k0 = 0; k0 < K; k0 += 32) {
#pragma unroll
    for (int p = 0; p < 2; p++) {
      int idx = tid + (p << 8);
      int row = idx >> 2;
      int kof = (idx & 3) << 3;
      *(bf16x8*)&As[row * 40 + kof] = *(const bf16x8*)&A[(size_t)(m0 + row) * K + k0 + kof];
      *(bf16x8*)&Bs[row * 40 + kof] = *(const bf16x8*)&Bm[(size_t)(n0 + row) * K + k0 + kof];
    }
    __syncthreads();
    bf16x8 af[4], bfv[4];
#pragma unroll
    for (int i = 0; i < 4; i++) af[i] = *(const bf16x8*)&As[(wr * 64 + i * 16 + r) * 40 + g * 8];
#pragma unroll
    for (int j = 0; j < 4; j++) bfv[j] = *(const bf16x8*)&Bs[(wc * 64 + j * 16 + r) * 40 + g * 8];
#pragma unroll
    for (int i = 0; i < 4; i++)
#pragma unroll
      for (int j = 0; j < 4; j++)
        acc[i][j] = __builtin_amdgcn_mfma_f32_16x16x32_bf16(af[i], bfv[j], acc[i][j], 0, 0, 0);
    __syncthreads();
  }

#pragma unroll
  for (int i = 0; i < 4; i++) {
#pragma unroll
    for (int j = 0; j < 4; j++) {
      int c = n0 + wc * 64 + j * 16 + r;
#pragma unroll
      for (int e = 0; e < 4; e++) {
        int mrow = m0 + wr * 64 + i * 16 + g * 4 + e;
        float val = acc[i][j][e];
        if constexpr (MODE == 0) {
          int which = c / 768;
          int cc = c - which * 768;
          int h = cc >> 6, d = cc & 63;
          int b = mrow >> 10, n = mrow & 1023;
          size_t bh = (size_t)(b * Hh + h);
          if (which == 0)      q_bf[(bh * Nn + n) * HD + d] = (bf16_t)val;
          else if (which == 1) k_bf[(bh * Nn + n) * HD + d] = (bf16_t)val;
          else                 vT_bf[(bh * HD + d) * Nn + n] = (bf16_t)val;
        } else {
          outF[(size_t)mrow * N + c] = val + bias[c];
        }
      }
    }
  }
}

// ---------------- per-(b,h,n) bias MLP -> {1+b0, b1, -b2/N, 0} -----------
__global__ __launch_bounds__(256) void bias_mlp(
    const bf16_t* __restrict__ qb, const bf16_t* __restrict__ kb,
    const float* __restrict__ w1, const float* __restrict__ b1,
    const float* __restrict__ w2, const float* __restrict__ b2,
    float* __restrict__ bias4) {
  __shared__ float w1s[32 * 129];
  __shared__ float qks[8][128];
  __shared__ float h1s[8][32];
  const int t = threadIdx.x;
#pragma unroll
  for (int p = 0; p < 16; p++) {
    int idx = p * 256 + t;
    w1s[(idx >> 7) * 129 + (idx & 127)] = w1[idx];
  }
  const int rl = t >> 5, u = t & 31;
  const int rowg = blockIdx.x * 8 + rl;
  {
    int i4 = u * 4;
    const bf16_t* src = (i4 < 64) ? (qb + (size_t)rowg * HD + i4)
                                  : (kb + (size_t)rowg * HD + (i4 - 64));
    bf16x4 vv = *(const bf16x4*)src;
#pragma unroll
    for (int z = 0; z < 4; z++) qks[rl][i4 + z] = (float)vv[z];
  }
  __syncthreads();
  float accv = b1[u];
#pragma unroll 8
  for (int i = 0; i < 128; i++) accv += qks[rl][i] * w1s[u * 129 + i];
  h1s[rl][u] = fmaxf(accv, 0.f);
  __syncthreads();
  if (u < 4) {
    float outv = 0.f;
    if (u < 3) {
      float s = b2[u];
#pragma unroll
      for (int j = 0; j < 32; j++) s += w2[u * 32 + j] * h1s[rl][j];
      float v = fabsf(s);
      outv = (u == 0) ? (1.f + v) : ((u == 1) ? v : -v * (1.f / (float)Nn));
    }
    bias4[(size_t)rowg * 4 + u] = outv;
  }
}

// ---------------- vsum[b][h*64+d] = sum_n v[b,h,n,d] (one wave each) -----
__global__ __launch_bounds__(256) void vsum_k(
    const bf16_t* __restrict__ vT, float* __restrict__ vsum) {
  const int wid = (blockIdx.x * 256 + threadIdx.x) >> 6;  // 0..3071
  const int lane = threadIdx.x & 63;
  const int b = wid / 768, c = wid % 768;
  const int h = c >> 6, d = c & 63;
  const bf16_t* vp = vT + ((size_t)((b * Hh + h) * HD + d)) * Nn + lane * 16;
  bf16x8 v0 = *(const bf16x8*)vp;
  bf16x8 v1 = *(const bf16x8*)(vp + 8);
  float s = 0.f;
#pragma unroll
  for (int j = 0; j < 8; j++) s += (float)v0[j] + (float)v1[j];
#pragma unroll
  for (int sh = 1; sh < 64; sh <<= 1) s += __shfl_xor(s, sh, 64);
  if (lane == 0) vsum[wid] = s;
}

// ---------------- flash_all v2: prefetched, no-max softmax ---------------
// Block = 128 thr (2 waves) = one 16-row tile; wave w owns cols [512w,+512).
// Pass 1: sum of exp(l) only (no max), K register double-buffered.
// Pass 2: recompute l (K from L2), prev register double-buffered, cur write,
//         LDS-transposed P (double-buffered), pre-blended PV MFMA.
// No-max safety: logits clamped at 30 (true |l| ~ <4 for this data; softmax
// without max-shift is mathematically identical, fp32-safe to l<=85).
__global__ __launch_bounds__(128, 3) void flash_all(
    const bf16_t* __restrict__ qb, const bf16_t* __restrict__ kb,
    const bf16_t* __restrict__ vT, const float* __restrict__ prev,
    const float* __restrict__ bias4, const float* __restrict__ vsum,
    float* __restrict__ cur, bf16_t* __restrict__ Ob) {
  __shared__ bf16_t pbuf[2][2][16 * 72];  // [wave][dbuf][row*72+col]
  __shared__ f32x4 opart[4][64];
  __shared__ float ssum[2][16];
  const int tile0 = blockIdx.x;
  const int tile = (tile0 & 7) * 384 + (tile0 >> 3);  // XCD-bijective swizzle
  const int bh = tile >> 6, mt = tile & 63;
  const int w = threadIdx.x >> 6, lane = threadIdx.x & 63;
  const int g = lane >> 4, r = lane & 15;
  const int row0 = mt << 4;
  const int colbase = w << 9;

  const bf16_t* qp = qb + ((size_t)bh * Nn + row0) * HD;
  const bf16_t* kp = kb + (size_t)bh * Nn * HD;
  const bf16_t* vp = vT + (size_t)bh * HD * Nn;
  // pre-scaled Q fragments (x0.125 exact in bf16)
  bf16x8 qa0 = *(const bf16x8*)&qp[r * HD + g * 8];
  bf16x8 qa1 = *(const bf16x8*)&qp[r * HD + g * 8 + 32];
  bf16x8 a0, a1;
#pragma unroll
  for (int j = 0; j < 8; j++) {
    a0[j] = (bf16_t)((float)qa0[j] * 0.125f);
    a1[j] = (bf16_t)((float)qa1[j] * 0.125f);
  }

  const f32x4 fz = {0.f, 0.f, 0.f, 0.f};
  float s_[4] = {0.f, 0.f, 0.f, 0.f};

  // ---- pass 1: sum of exp(l), K double-buffered ----
  bf16x8 kbuf[2][8];
#pragma unroll
  for (int sub = 0; sub < 4; sub++) {
    const bf16_t* kr = &kp[(size_t)(colbase + (sub << 4) + r) * HD + g * 8];
    kbuf[0][sub * 2] = *(const bf16x8*)kr;
    kbuf[0][sub * 2 + 1] = *(const bf16x8*)(kr + 32);
  }
#pragma unroll
  for (int t = 0; t < 8; t++) {
    if (t < 7) {
      const int c1 = colbase + ((t + 1) << 6);
#pragma unroll
      for (int sub = 0; sub < 4; sub++) {
        const bf16_t* kr = &kp[(size_t)(c1 + (sub << 4) + r) * HD + g * 8];
        kbuf[(t + 1) & 1][sub * 2] = *(const bf16x8*)kr;
        kbuf[(t + 1) & 1][sub * 2 + 1] = *(const bf16x8*)(kr + 32);
      }
    }
#pragma unroll
    for (int sub = 0; sub < 4; sub++) {
      f32x4 z = __builtin_amdgcn_mfma_f32_16x16x32_bf16(a0, kbuf[t & 1][sub * 2], fz, 0, 0, 0);
      f32x4 l = __builtin_amdgcn_mfma_f32_16x16x32_bf16(a1, kbuf[t & 1][sub * 2 + 1], z, 0, 0, 0);
#pragma unroll
      for (int e = 0; e < 4; e++) s_[e] += __expf(fminf(l[e], 30.f));
    }
  }
  // cross-lane (16 r-lanes) + cross-wave sum
#pragma unroll
  for (int sh = 1; sh < 16; sh <<= 1)
#pragma unroll
    for (int e = 0; e < 4; e++) s_[e] += __shfl_xor(s_[e], sh, 64);
  if (r == 0) {
#pragma unroll
    for (int e = 0; e < 4; e++) ssum[w][g * 4 + e] = s_[e];
  }
  __syncthreads();
  float inv[4];
#pragma unroll
  for (int e = 0; e < 4; e++)
    inv[e] = 1.f / (ssum[0][g * 4 + e] + ssum[1][g * 4 + e]);

  // ---- pass 2: recompute, cur write, pre-blended PV ----
  const float4 bvr = *(const float4*)&bias4[((size_t)bh * 1024 + row0 + r) * 4];
  const float b0c = bvr.x, b1c = bvr.y;
  float* cp = cur + (size_t)bh * Nn * Nn + (size_t)row0 * Nn;
  const float* ppv = prev + (size_t)bh * Nn * Nn + (size_t)row0 * Nn;
  f32x4 oacc[4] = {fz, fz, fz, fz};

  float4 pvb[2][4];
  {
    const float* pr = &ppv[(size_t)r * Nn + colbase + g * 8];
    pvb[0][0] = *(const float4*)pr;
    pvb[0][1] = *(const float4*)(pr + 4);
    pvb[0][2] = *(const float4*)(pr + 32);
    pvb[0][3] = *(const float4*)(pr + 36);
  }
#pragma unroll
  for (int t = 0; t < 8; t++) {
    const int c0 = colbase + (t << 6);
    if (t < 7) {
      const float* pr = &ppv[(size_t)r * Nn + c0 + 64 + g * 8];
      pvb[(t + 1) & 1][0] = *(const float4*)pr;
      pvb[(t + 1) & 1][1] = *(const float4*)(pr + 4);
      pvb[(t + 1) & 1][2] = *(const float4*)(pr + 32);
      pvb[(t + 1) & 1][3] = *(const float4*)(pr + 36);
    }
    // recompute logits (K from L1/L2 — just read in pass 1, XCD-local)
    bf16_t* pb = pbuf[w][t & 1];
#pragma unroll
    for (int sub = 0; sub < 4; sub++) {
      const bf16_t* kr = &kp[(size_t)(c0 + (sub << 4) + r) * HD + g * 8];
      bf16x8 b0 = *(const bf16x8*)kr;
      bf16x8 b1 = *(const bf16x8*)(kr + 32);
      f32x4 z = __builtin_amdgcn_mfma_f32_16x16x32_bf16(a0, b0, fz, 0, 0, 0);
      f32x4 l = __builtin_amdgcn_mfma_f32_16x16x32_bf16(a1, b1, z, 0, 0, 0);
#pragma unroll
      for (int e = 0; e < 4; e++) {
        float p = __expf(fminf(l[e], 30.f)) * inv[e];
        cp[(size_t)(g * 4 + e) * Nn + c0 + (sub << 4) + r] = p;
        pb[(g * 4 + e) * 72 + (sub << 4) + r] = (bf16_t)p;
      }
    }
    bf16x8 pa0 = *(bf16x8*)&pb[r * 72 + g * 8];
    bf16x8 pa1 = *(bf16x8*)&pb[r * 72 + 32 + g * 8];
    float4 q0 = pvb[t & 1][0], q1 = pvb[t & 1][1];
    float4 q2 = pvb[t & 1][2], q3 = pvb[t & 1][3];
    bf16x8 ab0, ab1;
    ab0[0] = (bf16_t)(b0c * (float)pa0[0] + b1c * q0.x);
    ab0[1] = (bf16_t)(b0c * (float)pa0[1] + b1c * q0.y);
    ab0[2] = (bf16_t)(b0c * (float)pa0[2] + b1c * q0.z);
    ab0[3] = (bf16_t)(b0c * (float)pa0[3] + b1c * q0.w);
    ab0[4] = (bf16_t)(b0c * (float)pa0[4] + b1c * q1.x);
    ab0[5] = (bf16_t)(b0c * (float)pa0[5] + b1c * q1.y);
    ab0[6] = (bf16_t)(b0c * (float)pa0[6] + b1c * q1.z);
    ab0[7] = (bf16_t)(b0c * (float)pa0[7] + b1c * q1.w);
    ab1[0] = (bf16_t)(b0c * (float)pa1[0] + b1c * q2.x);
    ab1[1] = (bf16_t)(b0c * (float)pa1[1] + b1c * q2.y);
    ab1[2] = (bf16_t)(b0c * (float)pa1[2] + b1c * q2.z);
    ab1[3] = (bf16_t)(b0c * (float)pa1[3] + b1c * q2.w);
    ab1[4] = (bf16_t)(b0c * (float)pa1[4] + b1c * q3.x);
    ab1[5] = (bf16_t)(b0c * (float)pa1[5] + b1c * q3.y);
    ab1[6] = (bf16_t)(b0c * (float)pa1[6] + b1c * q3.z);
    ab1[7] = (bf16_t)(b0c * (float)pa1[7] + b1c * q3.w);
#pragma unroll
    for (int d0 = 0; d0 < 4; d0++) {
      const bf16_t* vr = &vp[(size_t)((d0 << 4) + r) * Nn + c0 + g * 8];
      bf16x8 vb0 = *(const bf16x8*)vr;
      bf16x8 vb1 = *(const bf16x8*)(vr + 32);
      oacc[d0] = __builtin_amdgcn_mfma_f32_16x16x32_bf16(ab0, vb0, oacc[d0], 0, 0, 0);
      oacc[d0] = __builtin_amdgcn_mfma_f32_16x16x32_bf16(ab1, vb1, oacc[d0], 0, 0, 0);
    }
  }

  // ---- epilogue: cross-wave combine + vsum term + store ----
  if (w == 1) {
#pragma unroll
    for (int d0 = 0; d0 < 4; d0++) opart[d0][lane] = oacc[d0];
  }
  __syncthreads();
  if (w == 0) {
    const int b = bh / Hh, h = bh % Hh;
    float bz[4];
#pragma unroll
    for (int e = 0; e < 4; e++)
      bz[e] = bias4[((size_t)bh * 1024 + row0 + g * 4 + e) * 4 + 2];
#pragma unroll
    for (int d0 = 0; d0 < 4; d0++) {
      float vs = vsum[b * Cc + h * HD + (d0 << 4) + r];
      f32x4 tot = oacc[d0] + opart[d0][lane];
#pragma unroll
      for (int e = 0; e < 4; e++)
        Ob[(size_t)(b * Nn + row0 + g * 4 + e) * Cc + h * HD + (d0 << 4) + r] =
            (bf16_t)(tot[e] + bz[e] * vs);
    }
  }
}

// -------------------------------------------------------------------------
extern "C" void kernel_launch(void* const* d_in, const int* in_sizes, int n_in,
                              void* d_out, int out_size, void* d_ws, size_t ws_size,
                              hipStream_t stream) {
  const float* x      = (const float*)d_in[0];
  const float* prev   = (const float*)d_in[1];
  const float* qkv_w  = (const float*)d_in[2];
  const float* proj_w = (const float*)d_in[3];
  const float* proj_b = (const float*)d_in[4];
  const float* bp_w1  = (const float*)d_in[5];
  const float* bp_b1  = (const float*)d_in[6];
  const float* bp_w2  = (const float*)d_in[7];
  const float* bp_w2b = (const float*)d_in[8];

  float* out0 = (float*)d_out;
  float* cur  = out0 + OUT0;

  char* ws = (char*)d_ws;
  bf16_t* xb    = (bf16_t*)(ws + 0);          // dead after gemm0 -> Ob
  bf16_t* Ob    = (bf16_t*)(ws + 0);          // 6291456
  bf16_t* qwb   = (bf16_t*)(ws + 6291456);    // dead after gemm0 -> vsum
  float*  vsum  = (float*)(ws + 6291456);     // 12288
  bf16_t* pwb   = (bf16_t*)(ws + 9830400);
  bf16_t* qbf   = (bf16_t*)(ws + 11010048);
  bf16_t* kbf   = (bf16_t*)(ws + 17301504);
  bf16_t* vtb   = (bf16_t*)(ws + 23592960);
  float*  bias4 = (float*)(ws + 29884416);    // 786432 -> end 30670848
  if (ws_size < 30670848) return;

  convert_all<<<5376, 256, 0, stream>>>(x, qkv_w, proj_w, xb, qwb, pwb);
  gemm_bt<0><<<(4096 / 128) * (2304 / 128), 256, 0, stream>>>(
      xb, qwb, 2304, 768, qbf, kbf, vtb, nullptr, nullptr);
  bias_mlp<<<49152 / 8, 256, 0, stream>>>(qbf, kbf, bp_w1, bp_b1, bp_w2, bp_w2b, bias4);
  vsum_k<<<768, 256, 0, stream>>>(vtb, vsum);
  flash_all<<<3072, 128, 0, stream>>>(qbf, kbf, vtb, prev, bias4, vsum, cur, Ob);
  gemm_bt<1><<<(4096 / 128) * (768 / 128), 256, 0, stream>>>(
      Ob, pwb, 768, 768, nullptr, nullptr, nullptr, out0, proj_b);
}

// Round 8
// 292.849 us; speedup vs baseline: 1.1109x; 1.1109x over previous
//
#include <hip/hip_runtime.h>

typedef __bf16 bf16_t;
typedef __bf16 bf16x8 __attribute__((ext_vector_type(8)));
typedef __bf16 bf16x4 __attribute__((ext_vector_type(4)));
typedef float f32x4 __attribute__((ext_vector_type(4)));

static constexpr int Bb = 4, Hh = 12, Nn = 1024, Cc = 768, HD = 64;
static constexpr int OUT0 = Bb * Nn * Cc;  // 3145728 floats

// ---------------- convert fp32 -> bf16 (x, qkv_w, proj_w) ----------------
__global__ __launch_bounds__(256) void convert_all(
    const float* __restrict__ x, const float* __restrict__ qw, const float* __restrict__ pw,
    bf16_t* __restrict__ xb, bf16_t* __restrict__ qwb, bf16_t* __restrict__ pwb) {
  const int NX = (Bb * Nn * Cc) / 4;  // 786432 float4s
  const int NQ = (3 * Cc * Cc) / 4;   // 442368
  int i = blockIdx.x * 256 + threadIdx.x;
  const float4* src;
  bf16_t* dst;
  int off;
  if (i < NX) { src = (const float4*)x; dst = xb; off = i; }
  else if (i < NX + NQ) { src = (const float4*)qw; dst = qwb; off = i - NX; }
  else { src = (const float4*)pw; dst = pwb; off = i - NX - NQ; }
  float4 v = src[off];
  bf16x4 o;
  o[0] = (bf16_t)v.x; o[1] = (bf16_t)v.y; o[2] = (bf16_t)v.z; o[3] = (bf16_t)v.w;
  *(bf16x4*)(dst + (size_t)off * 4) = o;
}

// ---------------- 128x128-tile bf16 MFMA GEMM -----------------------------
template <int MODE>
__global__ __launch_bounds__(256) void gemm_bt(
    const bf16_t* __restrict__ A, const bf16_t* __restrict__ Bm, int N, int K,
    bf16_t* __restrict__ q_bf, bf16_t* __restrict__ k_bf, bf16_t* __restrict__ vT_bf,
    float* __restrict__ outF, const float* __restrict__ bias) {
  __shared__ bf16_t As[128 * 40];
  __shared__ bf16_t Bs[128 * 40];
  const int tid = threadIdx.x;
  const int lane = tid & 63;
  const int w = tid >> 6;
  const int wr = w >> 1, wc = w & 1;
  const int g = lane >> 4, r = lane & 15;
  const int ntiles = N >> 7;
  const int m0 = (blockIdx.x / ntiles) << 7;
  const int n0 = (blockIdx.x % ntiles) << 7;

  const f32x4 fz = {0.f, 0.f, 0.f, 0.f};
  f32x4 acc[4][4];
#pragma unroll
  for (int i = 0; i < 4; i++)
#pragma unroll
    for (int j = 0; j < 4; j++) acc[i][j] = fz;

  for (int k0 = 0; k0 < K; k0 += 32) {
#pragma unroll
    for (int p = 0; p < 2; p++) {
      int idx = tid + (p << 8);
      int row = idx >> 2;
      int kof = (idx & 3) << 3;
      *(bf16x8*)&As[row * 40 + kof] = *(const bf16x8*)&A[(size_t)(m0 + row) * K + k0 + kof];
      *(bf16x8*)&Bs[row * 40 + kof] = *(const bf16x8*)&Bm[(size_t)(n0 + row) * K + k0 + kof];
    }
    __syncthreads();
    bf16x8 af[4], bfv[4];
#pragma unroll
    for (int i = 0; i < 4; i++) af[i] = *(const bf16x8*)&As[(wr * 64 + i * 16 + r) * 40 + g * 8];
#pragma unroll
    for (int j = 0; j < 4; j++) bfv[j] = *(const bf16x8*)&Bs[(wc * 64 + j * 16 + r) * 40 + g * 8];
#pragma unroll
    for (int i = 0; i < 4; i++)
#pragma unroll
      for (int j = 0; j < 4; j++)
        acc[i][j] = __builtin_amdgcn_mfma_f32_16x16x32_bf16(af[i], bfv[j], acc[i][j], 0, 0, 0);
    __syncthreads();
  }

#pragma unroll
  for (int i = 0; i < 4; i++) {
#pragma unroll
    for (int j = 0; j < 4; j++) {
      int c = n0 + wc * 64 + j * 16 + r;
#pragma unroll
      for (int e = 0; e < 4; e++) {
        int mrow = m0 + wr * 64 + i * 16 + g * 4 + e;
        float val = acc[i][j][e];
        if constexpr (MODE == 0) {
          int which = c / 768;
          int cc = c - which * 768;
          int h = cc >> 6, d = cc & 63;
          int b = mrow >> 10, n = mrow & 1023;
          size_t bh = (size_t)(b * Hh + h);
          if (which == 0)      q_bf[(bh * Nn + n) * HD + d] = (bf16_t)val;
          else if (which == 1) k_bf[(bh * Nn + n) * HD + d] = (bf16_t)val;
          else                 vT_bf[(bh * HD + d) * Nn + n] = (bf16_t)val;
        } else {
          outF[(size_t)mrow * N + c] = val + bias[c];
        }
      }
    }
  }
}

// ---------------- per-(b,h,n) bias MLP -> {1+b0, b1, -b2/N, 0} -----------
__global__ __launch_bounds__(256) void bias_mlp(
    const bf16_t* __restrict__ qb, const bf16_t* __restrict__ kb,
    const float* __restrict__ w1, const float* __restrict__ b1,
    const float* __restrict__ w2, const float* __restrict__ b2,
    float* __restrict__ bias4) {
  __shared__ float w1s[32 * 129];
  __shared__ float qks[8][128];
  __shared__ float h1s[8][32];
  const int t = threadIdx.x;
#pragma unroll
  for (int p = 0; p < 16; p++) {
    int idx = p * 256 + t;
    w1s[(idx >> 7) * 129 + (idx & 127)] = w1[idx];
  }
  const int rl = t >> 5, u = t & 31;
  const int rowg = blockIdx.x * 8 + rl;
  {
    int i4 = u * 4;
    const bf16_t* src = (i4 < 64) ? (qb + (size_t)rowg * HD + i4)
                                  : (kb + (size_t)rowg * HD + (i4 - 64));
    bf16x4 vv = *(const bf16x4*)src;
#pragma unroll
    for (int z = 0; z < 4; z++) qks[rl][i4 + z] = (float)vv[z];
  }
  __syncthreads();
  float accv = b1[u];
#pragma unroll 8
  for (int i = 0; i < 128; i++) accv += qks[rl][i] * w1s[u * 129 + i];
  h1s[rl][u] = fmaxf(accv, 0.f);
  __syncthreads();
  if (u < 4) {
    float outv = 0.f;
    if (u < 3) {
      float s = b2[u];
#pragma unroll
      for (int j = 0; j < 32; j++) s += w2[u * 32 + j] * h1s[rl][j];
      float v = fabsf(s);
      outv = (u == 0) ? (1.f + v) : ((u == 1) ? v : -v * (1.f / (float)Nn));
    }
    bias4[(size_t)rowg * 4 + u] = outv;
  }
}

// ---------------- vsum[b][h*64+d] = sum_n v[b,h,n,d] (one wave each) -----
__global__ __launch_bounds__(256) void vsum_k(
    const bf16_t* __restrict__ vT, float* __restrict__ vsum) {
  const int wid = (blockIdx.x * 256 + threadIdx.x) >> 6;  // 0..3071
  const int lane = threadIdx.x & 63;
  const int b = wid / 768, c = wid % 768;
  const int h = c >> 6, d = c & 63;
  const bf16_t* vp = vT + ((size_t)((b * Hh + h) * HD + d)) * Nn + lane * 16;
  bf16x8 v0 = *(const bf16x8*)vp;
  bf16x8 v1 = *(const bf16x8*)(vp + 8);
  float s = 0.f;
#pragma unroll
  for (int j = 0; j < 8; j++) s += (float)v0[j] + (float)v1[j];
#pragma unroll
  for (int sh = 1; sh < 64; sh <<= 1) s += __shfl_xor(s, sh, 64);
  if (lane == 0) vsum[wid] = s;
}

// ---------------- flash_cur: single-pass QK^T->softmax->cur + O1=cur@v ---
// 256 thr (4 waves) per 16-row tile. Wave w: cols [256w,+256) in acc[16].
// One softmax (register tree + 1 shuffle chain + LDS cross-wave), scattered
// cur write from regs, bf16 P -> swizzled LDS, barrier, PV (wave w owns
// d-cols [16w,+16) over full K from LDS P + L2-resident vT).
__global__ __launch_bounds__(256, 4) void flash_cur(
    const bf16_t* __restrict__ qb, const bf16_t* __restrict__ kb,
    const bf16_t* __restrict__ vT, float* __restrict__ cur,
    bf16_t* __restrict__ O1) {
  __shared__ bf16_t Pl[16 * 1024];   // swizzled: byte ^= (row&7)<<4
  __shared__ float redmax[16][4];
  __shared__ float redsum[16][4];
  const int bid = blockIdx.x;
  const int tile = (bid & 7) * 384 + (bid >> 3);  // XCD-bijective (3072%8==0)
  const int bh = tile >> 6, mt = tile & 63;
  const int lane = threadIdx.x & 63, w = threadIdx.x >> 6;
  const int g = lane >> 4, r = lane & 15;
  const int row0 = mt << 4;

  const bf16_t* qp = qb + ((size_t)bh * Nn + row0) * HD;
  const bf16_t* kp = kb + (size_t)bh * Nn * HD;
  const bf16_t* vp = vT + (size_t)bh * HD * Nn;
  bf16x8 a0 = *(const bf16x8*)&qp[r * HD + g * 8];
  bf16x8 a1 = *(const bf16x8*)&qp[r * HD + g * 8 + 32];
  const f32x4 fz = {0.f, 0.f, 0.f, 0.f};
  f32x4 acc[16];
#pragma unroll
  for (int t = 0; t < 16; t++) {
    int col = (w << 8) + (t << 4) + r;
    bf16x8 b0 = *(const bf16x8*)&kp[(size_t)col * HD + g * 8];
    bf16x8 b1 = *(const bf16x8*)&kp[(size_t)col * HD + g * 8 + 32];
    f32x4 z = __builtin_amdgcn_mfma_f32_16x16x32_bf16(a0, b0, fz, 0, 0, 0);
    acc[t] = __builtin_amdgcn_mfma_f32_16x16x32_bf16(a1, b1, z, 0, 0, 0);
  }
  const float scale = 0.125f;
  float mj[4] = {-3.0e38f, -3.0e38f, -3.0e38f, -3.0e38f};
#pragma unroll
  for (int t = 0; t < 16; t++)
#pragma unroll
    for (int e = 0; e < 4; e++) {
      acc[t][e] *= scale;
      mj[e] = fmaxf(mj[e], acc[t][e]);
    }
#pragma unroll
  for (int s = 1; s < 16; s <<= 1)
#pragma unroll
    for (int e = 0; e < 4; e++) mj[e] = fmaxf(mj[e], __shfl_xor(mj[e], s, 64));
  if (r == 0) {
#pragma unroll
    for (int e = 0; e < 4; e++) redmax[g * 4 + e][w] = mj[e];
  }
  __syncthreads();
  float rm[4];
#pragma unroll
  for (int e = 0; e < 4; e++) {
    float v = fmaxf(redmax[g * 4 + e][0], redmax[g * 4 + e][1]);
    rm[e] = fmaxf(v, fmaxf(redmax[g * 4 + e][2], redmax[g * 4 + e][3]));
  }
  float sj[4] = {0.f, 0.f, 0.f, 0.f};
#pragma unroll
  for (int t = 0; t < 16; t++)
#pragma unroll
    for (int e = 0; e < 4; e++) {
      float ev = __expf(acc[t][e] - rm[e]);
      acc[t][e] = ev;
      sj[e] += ev;
    }
#pragma unroll
  for (int s = 1; s < 16; s <<= 1)
#pragma unroll
    for (int e = 0; e < 4; e++) sj[e] += __shfl_xor(sj[e], s, 64);
  if (r == 0) {
#pragma unroll
    for (int e = 0; e < 4; e++) redsum[g * 4 + e][w] = sj[e];
  }
  __syncthreads();
  float inv[4];
#pragma unroll
  for (int e = 0; e < 4; e++)
    inv[e] = 1.f / (redsum[g * 4 + e][0] + redsum[g * 4 + e][1] +
                    redsum[g * 4 + e][2] + redsum[g * 4 + e][3]);
  // cur write (scattered, from regs) + bf16 P -> swizzled LDS
  float* op = cur + (size_t)bh * Nn * Nn;
#pragma unroll
  for (int t = 0; t < 16; t++) {
    int col = (w << 8) + (t << 4) + r;
#pragma unroll
    for (int e = 0; e < 4; e++) {
      float p = acc[t][e] * inv[e];
      int row = g * 4 + e;
      op[(size_t)(row0 + row) * Nn + col] = p;
      int byteoff = (row * 2048 + col * 2) ^ ((row & 7) << 4);
      *(bf16_t*)((char*)Pl + byteoff) = (bf16_t)p;
    }
  }
  __syncthreads();
  // PV: wave w -> d-cols [16w,+16); 4 independent k-chains
  const bf16_t* vrow = vp + (size_t)((w << 4) + r) * Nn;
  f32x4 c0 = fz, c1 = fz, c2 = fz, c3 = fz;
#pragma unroll
  for (int ks = 0; ks < 8; ks++) {
    int kA = ks << 5;
#pragma unroll
    for (int q = 0; q < 4; q++) {
      int k0 = (q << 8) + kA;
      bf16x8 pa = *(bf16x8*)((char*)Pl + ((r * 2048 + (k0 + g * 8) * 2) ^ ((r & 7) << 4)));
      bf16x8 vb = *(const bf16x8*)&vrow[k0 + g * 8];
      if (q == 0) c0 = __builtin_amdgcn_mfma_f32_16x16x32_bf16(pa, vb, c0, 0, 0, 0);
      else if (q == 1) c1 = __builtin_amdgcn_mfma_f32_16x16x32_bf16(pa, vb, c1, 0, 0, 0);
      else if (q == 2) c2 = __builtin_amdgcn_mfma_f32_16x16x32_bf16(pa, vb, c2, 0, 0, 0);
      else c3 = __builtin_amdgcn_mfma_f32_16x16x32_bf16(pa, vb, c3, 0, 0, 0);
    }
  }
  f32x4 osum = (c0 + c1) + (c2 + c3);
  const int b = bh / Hh, h = bh % Hh;
#pragma unroll
  for (int e = 0; e < 4; e++) {
    int nrow = row0 + g * 4 + e;
    O1[((size_t)(b * Nn + nrow)) * Cc + h * HD + (w << 4) + r] = (bf16_t)osum[e];
  }
}

// ---------------- prevv: O2 = prev @ v (streaming GEMM, dbuf LDS) --------
// 256 thr (4 waves); tile = 32 rows x 64 d; k-step 128, 8 steps.
// Wave w: rows (w>>1)*16..+16, d-cols (w&1)*32..+32.
__global__ __launch_bounds__(256) void prevv(
    const float* __restrict__ prev, const bf16_t* __restrict__ vT,
    bf16_t* __restrict__ O2) {
  __shared__ bf16_t As[2][32 * 136];  // pad 128->136
  const int tid = threadIdx.x, lane = tid & 63, w = tid >> 6;
  const int g = lane >> 4, r = lane & 15;
  const int bid2 = (blockIdx.x & 7) * 192 + (blockIdx.x >> 3);  // XCD swizzle
  const int bh = bid2 >> 5, tile = bid2 & 31;
  const int n0 = tile << 5;
  const float* ap = prev + (size_t)bh * Nn * Nn + (size_t)(n0 + (tid >> 3)) * Nn + ((tid & 7) << 2);
  const bf16_t* vp = vT + ((size_t)bh * HD + ((w & 1) << 5)) * Nn;
  const int srow = tid >> 3, scol = (tid & 7) << 2;
  const int wrow = (w >> 1) << 4;

  const f32x4 fz = {0.f, 0.f, 0.f, 0.f};
  f32x4 accA = fz, accB = fz;
  float4 rg[2][4];
#pragma unroll
  for (int j = 0; j < 4; j++) rg[0][j] = *(const float4*)&ap[j * 32];

#pragma unroll
  for (int t = 0; t < 8; t++) {
    // stage step-t data into LDS buf[t&1]
    bf16_t* dst = &As[t & 1][srow * 136 + scol];
#pragma unroll
    for (int j = 0; j < 4; j++) {
      float4 f = rg[t & 1][j];
      bf16x4 o;
      o[0] = (bf16_t)f.x; o[1] = (bf16_t)f.y; o[2] = (bf16_t)f.z; o[3] = (bf16_t)f.w;
      *(bf16x4*)(dst + j * 32) = o;
    }
    // prefetch step t+1
    if (t < 7) {
#pragma unroll
      for (int j = 0; j < 4; j++)
        rg[(t + 1) & 1][j] = *(const float4*)&ap[(t + 1) * 128 + j * 32];
    }
    __syncthreads();
#pragma unroll
    for (int ks = 0; ks < 4; ks++) {
      bf16x8 af = *(const bf16x8*)&As[t & 1][(wrow + r) * 136 + (ks << 5) + g * 8];
      bf16x8 b0 = *(const bf16x8*)&vp[(size_t)r * Nn + (t << 7) + (ks << 5) + g * 8];
      bf16x8 b1 = *(const bf16x8*)&vp[(size_t)(16 + r) * Nn + (t << 7) + (ks << 5) + g * 8];
      accA = __builtin_amdgcn_mfma_f32_16x16x32_bf16(af, b0, accA, 0, 0, 0);
      accB = __builtin_amdgcn_mfma_f32_16x16x32_bf16(af, b1, accB, 0, 0, 0);
    }
  }
  const int b = bh / Hh, h = bh % Hh;
  const int dbase = h * HD + ((w & 1) << 5);
#pragma unroll
  for (int e = 0; e < 4; e++) {
    int nrow = n0 + wrow + g * 4 + e;
    O2[(size_t)(b * Nn + nrow) * Cc + dbase + r] = (bf16_t)accA[e];
    O2[(size_t)(b * Nn + nrow) * Cc + dbase + 16 + r] = (bf16_t)accB[e];
  }
}

// ---------------- proj GEMM with fused combine in A-staging --------------
// A[row][c] = b0*O1 + b1*O2 + (-b2/N)*vsum   (per-row b's, per-col vsum)
__global__ __launch_bounds__(256) void gemm_proj(
    const bf16_t* __restrict__ O1, const bf16_t* __restrict__ O2,
    const float* __restrict__ bias4, const float* __restrict__ vsum,
    const bf16_t* __restrict__ Bw, const float* __restrict__ pbias,
    float* __restrict__ outF) {
  __shared__ bf16_t As[128 * 40];
  __shared__ bf16_t Bs[128 * 40];
  const int tid = threadIdx.x, lane = tid & 63, w = tid >> 6;
  const int wr = w >> 1, wc = w & 1;
  const int g = lane >> 4, r = lane & 15;
  const int m0 = (blockIdx.x / 6) << 7;
  const int n0 = (blockIdx.x % 6) << 7;
  const f32x4 fz = {0.f, 0.f, 0.f, 0.f};
  f32x4 acc[4][4];
#pragma unroll
  for (int i = 0; i < 4; i++)
#pragma unroll
    for (int j = 0; j < 4; j++) acc[i][j] = fz;

  for (int k0 = 0; k0 < 768; k0 += 32) {
#pragma unroll
    for (int p = 0; p < 2; p++) {
      int idx = tid + (p << 8);
      int row = idx >> 2, kof = (idx & 3) << 3;
      int grow = m0 + row;
      int b = grow >> 10, n = grow & 1023;
      int c = k0 + kof, h = c >> 6;
      bf16x8 o1 = *(const bf16x8*)&O1[(size_t)grow * Cc + c];
      bf16x8 o2 = *(const bf16x8*)&O2[(size_t)grow * Cc + c];
      float4 bv = *(const float4*)&bias4[((size_t)(b * Hh + h) * Nn + n) * 4];
      float4 v0 = *(const float4*)&vsum[b * Cc + c];
      float4 v1 = *(const float4*)&vsum[b * Cc + c + 4];
      float vs[8] = {v0.x, v0.y, v0.z, v0.w, v1.x, v1.y, v1.z, v1.w};
      bf16x8 a;
#pragma unroll
      for (int j = 0; j < 8; j++)
        a[j] = (bf16_t)(bv.x * (float)o1[j] + bv.y * (float)o2[j] + bv.z * vs[j]);
      *(bf16x8*)&As[row * 40 + kof] = a;
      *(bf16x8*)&Bs[row * 40 + kof] = *(const bf16x8*)&Bw[(size_t)(n0 + row) * Cc + k0 + kof];
    }
    __syncthreads();
    bf16x8 af[4], bfv[4];
#pragma unroll
    for (int i = 0; i < 4; i++) af[i] = *(const bf16x8*)&As[(wr * 64 + i * 16 + r) * 40 + g * 8];
#pragma unroll
    for (int j = 0; j < 4; j++) bfv[j] = *(const bf16x8*)&Bs[(wc * 64 + j * 16 + r) * 40 + g * 8];
#pragma unroll
    for (int i = 0; i < 4; i++)
#pragma unroll
      for (int j = 0; j < 4; j++)
        acc[i][j] = __builtin_amdgcn_mfma_f32_16x16x32_bf16(af[i], bfv[j], acc[i][j], 0, 0, 0);
    __syncthreads();
  }
#pragma unroll
  for (int i = 0; i < 4; i++)
#pragma unroll
    for (int j = 0; j < 4; j++) {
      int c = n0 + wc * 64 + j * 16 + r;
#pragma unroll
      for (int e = 0; e < 4; e++) {
        int mrow = m0 + wr * 64 + i * 16 + g * 4 + e;
        outF[(size_t)mrow * Cc + c] = acc[i][j][e] + pbias[c];
      }
    }
}

// -------------------------------------------------------------------------
extern "C" void kernel_launch(void* const* d_in, const int* in_sizes, int n_in,
                              void* d_out, int out_size, void* d_ws, size_t ws_size,
                              hipStream_t stream) {
  const float* x      = (const float*)d_in[0];
  const float* prev   = (const float*)d_in[1];
  const float* qkv_w  = (const float*)d_in[2];
  const float* proj_w = (const float*)d_in[3];
  const float* proj_b = (const float*)d_in[4];
  const float* bp_w1  = (const float*)d_in[5];
  const float* bp_b1  = (const float*)d_in[6];
  const float* bp_w2  = (const float*)d_in[7];
  const float* bp_w2b = (const float*)d_in[8];

  float* out0 = (float*)d_out;
  float* cur  = out0 + OUT0;

  char* ws = (char*)d_ws;
  bf16_t* xb    = (bf16_t*)(ws + 0);          // dead after gemm0 -> O1
  bf16_t* O1b   = (bf16_t*)(ws + 0);          // 6291456
  bf16_t* qwb   = (bf16_t*)(ws + 6291456);    // dead after gemm0 -> vsum
  float*  vsum  = (float*)(ws + 6291456);     // 12288
  bf16_t* pwb   = (bf16_t*)(ws + 9830400);
  bf16_t* qbf   = (bf16_t*)(ws + 11010048);
  bf16_t* kbf   = (bf16_t*)(ws + 17301504);
  bf16_t* vtb   = (bf16_t*)(ws + 23592960);
  float*  bias4 = (float*)(ws + 29884416);
  bf16_t* O2b   = (bf16_t*)(ws + 30670848);   // 6291456 -> end 36962304
  if (ws_size < 36962304) return;

  convert_all<<<5376, 256, 0, stream>>>(x, qkv_w, proj_w, xb, qwb, pwb);
  gemm_bt<0><<<(4096 / 128) * (2304 / 128), 256, 0, stream>>>(
      xb, qwb, 2304, 768, qbf, kbf, vtb, nullptr, nullptr);
  bias_mlp<<<49152 / 8, 256, 0, stream>>>(qbf, kbf, bp_w1, bp_b1, bp_w2, bp_w2b, bias4);
  vsum_k<<<768, 256, 0, stream>>>(vtb, vsum);
  flash_cur<<<3072, 256, 0, stream>>>(qbf, kbf, vtb, cur, O1b);
  prevv<<<1536, 256, 0, stream>>>(prev, vtb, O2b);
  gemm_proj<<<32 * 6, 256, 0, stream>>>(O1b, O2b, bias4, vsum, pwb, proj_b, out0);
}